// Round 7
// baseline (10434.859 us; speedup 1.0000x reference)
//
#include <hip/hip_runtime.h>

#define B_ 8
#define N_ 4096
#define M_ 2048
#define K_ 32
#define BM_ (B_*M_)          // 16384
#define S_TOT (B_*M_*K_)     // 524288

typedef unsigned short u16;
typedef unsigned int   u32;
typedef unsigned long long u64;

// output element offsets (f32 elements): (new_pose, new_feat, new_normal, new_sh)
#define OUT1_OFF 49152       // new_feat
#define OUT2_OFF 2146304     // new_normal
#define OUT3_OFF 2195456     // new_sh

// ws byte offsets — TOTAL < 2.6 MiB
#define OFF_FPS   ((size_t)0)                 // 16384 int      = 64 KiB
#define OFF_NP    ((size_t)(64<<10))          // 16384*3 f32    = 192 KiB
#define OFF_KNN   ((size_t)(256<<10))         // 16384*32 int   = 2 MiB
#define OFF_ACC   ((size_t)(2432<<10))        // 5*256 f32      = 5 KiB
#define OFF_SCSH  ((size_t)(2560<<10))        // 5*256 f32      = 5 KiB

// ---------------- init: zero the stats accumulators (ws is poisoned every launch) ----------------
__global__ __launch_bounds__(256) void init_kernel(float* __restrict__ acc){
  int i = blockIdx.x*256 + threadIdx.x;
  if (i < 1280) acc[i] = 0.f;
}

// ---------------- FPS: 8 blocks, 512 threads, 8 pts/thread, exact-np f32 ----------------
__global__ __launch_bounds__(512) void fps_kernel(const float* __restrict__ pose, int* __restrict__ fps_idx){
  const int b = blockIdx.x;
  const float* P = pose + (size_t)b*N_*3;
  const int t = threadIdx.x;
  __shared__ float sX[N_], sY[N_], sZ[N_];
  __shared__ u32 wk[2][8];
  __shared__ int wi_[2][8];
  float px[8],py[8],pz[8],dd[8];
  #pragma unroll
  for (int i=0;i<8;++i){
    int p = t + (i<<9);
    float x = P[p*3+0]; float y = P[p*3+1]; float z = P[p*3+2];
    px[i]=x; py[i]=y; pz[i]=z; dd[i]=1e10f;
    sX[p]=x; sY[p]=y; sZ[p]=z;
  }
  if (t==0) fps_idx[(size_t)b*M_] = 0;
  __syncthreads();
  float cx = sX[0], cy = sY[0], cz = sZ[0];
  for (int s=1; s<M_; ++s){
    u32 bk = 0u; int bi = 0;
    #pragma unroll
    for (int i=0;i<8;++i){
      float dx=__fsub_rn(px[i],cx), dy=__fsub_rn(py[i],cy), dz=__fsub_rn(pz[i],cz);
      float d = __fadd_rn(__fadd_rn(__fmul_rn(dx,dx),__fmul_rn(dy,dy)),__fmul_rn(dz,dz));
      float nd = fminf(dd[i], d);
      dd[i] = nd;
      u32 k = __float_as_uint(nd);   // nd >= 0 -> bits order-preserving
      int gi = t + (i<<9);
      if (k > bk || (k == bk && gi < bi)){ bk = k; bi = gi; }
    }
    #pragma unroll
    for (int off=1; off<64; off<<=1){
      u32 ok_ = __shfl_xor(bk, off);
      int oi  = __shfl_xor(bi, off);
      if (ok_ > bk || (ok_ == bk && oi < bi)){ bk=ok_; bi=oi; }
    }
    const int par = s & 1;
    if ((t&63)==0){ wk[par][t>>6]=bk; wi_[par][t>>6]=bi; }
    __syncthreads();
    u32 fk = wk[par][0]; int fi = wi_[par][0];
    #pragma unroll
    for (int w=1; w<8; ++w){
      u32 ok_=wk[par][w]; int oi=wi_[par][w];
      if (ok_>fk || (ok_==fk && oi<fi)){ fk=ok_; fi=oi; }
    }
    fi &= (N_-1);
    cx = sX[fi]; cy = sY[fi]; cz = sZ[fi];
    if (t==0) fps_idx[(size_t)b*M_ + s] = fi;
  }
}

// ---------------- gather: f32 copies of new_pose/new_normal/new_sh ----------------
__global__ __launch_bounds__(256) void gather_kernel(const float* __restrict__ pose, const float* __restrict__ normal,
    const float* __restrict__ sh, const int* __restrict__ fps_idx, float* __restrict__ out, float* __restrict__ newpose){
  int bm = blockIdx.x*256 + threadIdx.x;
  if (bm >= BM_) return;
  int b = bm >> 11;
  int idx = fps_idx[bm] & (N_-1);
  size_t src = ((size_t)b*N_ + idx);
  #pragma unroll
  for (int c=0;c<3;++c){
    float v = pose[src*3+c];
    out[(size_t)bm*3+c] = v;
    newpose[(size_t)bm*3+c] = v;
    out[OUT2_OFF + (size_t)bm*3+c] = normal[src*3+c];
  }
  #pragma unroll
  for (int c=0;c<9;++c) out[OUT3_OFF + (size_t)bm*9+c] = sh[src*9+c];
}

// ---------------- KNN: one block (256 thr) per query, exact-np f32, stable top-32 ------
__global__ __launch_bounds__(256) void knn_kernel(const float* __restrict__ pose, const float* __restrict__ newpose,
    int* __restrict__ knn){
  const int bm = blockIdx.x;
  const int b = bm >> 11;
  const int tid = threadIdx.x;
  const float* P = pose + (size_t)b*N_*3;
  __shared__ u64 sw[4];
  float qx = newpose[(size_t)bm*3+0];
  float qy = newpose[(size_t)bm*3+1];
  float qz = newpose[(size_t)bm*3+2];
  float qq = __fadd_rn(__fadd_rn(__fmul_rn(qx,qx),__fmul_rn(qy,qy)),__fmul_rn(qz,qz));
  u64 key[16];
  #pragma unroll
  for (int j=0;j<16;++j){
    int c = tid*16 + j;
    float x = P[c*3+0];
    float y = P[c*3+1];
    float z = P[c*3+2];
    float pp = __fadd_rn(__fadd_rn(__fmul_rn(x,x),__fmul_rn(y,y)),__fmul_rn(z,z));
    float dt = __fadd_rn(__fadd_rn(__fmul_rn(qx,x),__fmul_rn(qy,y)),__fmul_rn(qz,z));
    float d2 = __fadd_rn(__fsub_rn(qq, __fmul_rn(2.0f,dt)), pp);
    u32 u = __float_as_uint(d2);
    u32 mk = ((int)u < 0) ? ~u : (u | 0x80000000u);   // monotone (d2 may round negative)
    key[j] = ((u64)mk << 32) | (u32)c;                // ties -> lowest index
  }
  u64 best = key[0];
  #pragma unroll
  for (int j=1;j<16;++j) best = (key[j] < best) ? key[j] : best;
  const int lane = tid & 63, wv = tid >> 6;
  for (int r=0; r<K_; ++r){
    u64 wb = best;
    #pragma unroll
    for (int off=1; off<64; off<<=1){
      u64 o = __shfl_xor(wb, off);
      wb = (o < wb) ? o : wb;
    }
    if (lane==0) sw[wv] = wb;
    __syncthreads();
    u64 g = sw[0];
    #pragma unroll
    for (int w=1; w<4; ++w) g = (sw[w] < g) ? sw[w] : g;
    int gi = (int)(u32)(g & 0xffffffffull);
    if (tid==0) knn[(size_t)bm*K_ + r] = gi;
    if (tid == (gi >> 4)){
      int jj = gi & 15;
      #pragma unroll
      for (int j=0;j<16;++j) if (j==jj) key[j] = 0xffffffffffffffffull;
      best = key[0];
      #pragma unroll
      for (int j=1;j<16;++j) best = (key[j] < best) ? key[j] : best;
    }
    __syncthreads();
  }
}

// ---------------- chain building blocks (weights read from global; uniform -> cache broadcast) ----
template<int CIN, int COUT>
__device__ __forceinline__ void dense(const float* __restrict__ W, const float* __restrict__ bias,
                                      const float* x, float* y){
  #pragma unroll
  for (int j=0;j<COUT;j+=4){
    float4 a = *(const float4*)(bias+j);
    #pragma unroll
    for (int c=0;c<CIN;++c){
      float4 w = *(const float4*)(W + c*COUT + j);
      a.x = fmaf(x[c], w.x, a.x); a.y = fmaf(x[c], w.y, a.y);
      a.z = fmaf(x[c], w.z, a.z); a.w = fmaf(x[c], w.w, a.w);
    }
    y[j]=a.x; y[j+1]=a.y; y[j+2]=a.z; y[j+3]=a.w;
  }
}
template<int C1, int C2, int COUT>
__device__ __forceinline__ void dense2(const float* __restrict__ W, const float* __restrict__ bias,
                                       const float* x1, const float* x2, float* y){
  #pragma unroll
  for (int j=0;j<COUT;j+=4){
    float4 a = *(const float4*)(bias+j);
    #pragma unroll
    for (int c=0;c<C1;++c){
      float4 w = *(const float4*)(W + c*COUT + j);
      a.x = fmaf(x1[c], w.x, a.x); a.y = fmaf(x1[c], w.y, a.y);
      a.z = fmaf(x1[c], w.z, a.z); a.w = fmaf(x1[c], w.w, a.w);
    }
    #pragma unroll
    for (int c=0;c<C2;++c){
      float4 w = *(const float4*)(W + (C1+c)*COUT + j);
      a.x = fmaf(x2[c], w.x, a.x); a.y = fmaf(x2[c], w.y, a.y);
      a.z = fmaf(x2[c], w.z, a.z); a.w = fmaf(x2[c], w.w, a.w);
    }
    y[j]=a.x; y[j+1]=a.y; y[j+2]=a.z; y[j+3]=a.w;
  }
}
template<int C>
__device__ __forceinline__ void bnrelu(const float* __restrict__ scsh, float* y){
  #pragma unroll
  for (int j=0;j<C;++j) y[j] = fmaxf(fmaf(scsh[j], y[j], scsh[128+j]), 0.f);
}

// PPF features for sample row s
__device__ __forceinline__ void ppf_feats(const float* __restrict__ pose, const float* __restrict__ normal,
    const int* __restrict__ knn, size_t s, float x0[5]){
  int bm = (int)(s >> 5), k = (int)(s & 31), b = bm >> 11;
  const int* kn = knn + (size_t)bm*K_;
  int i0 = kn[0] & (N_-1);
  int ik = kn[k] & (N_-1);
  const float* Pb = pose + (size_t)b*N_*3;
  const float* Nb = normal + (size_t)b*N_*3;
  float p0x=Pb[i0*3], p0y=Pb[i0*3+1], p0z=Pb[i0*3+2];
  float pkx=Pb[ik*3], pky=Pb[ik*3+1], pkz=Pb[ik*3+2];
  float n0x=Nb[i0*3], n0y=Nb[i0*3+1], n0z=Nb[i0*3+2];
  float nkx=Nb[ik*3], nky=Nb[ik*3+1], nkz=Nb[ik*3+2];
  float dx=pkx-p0x, dy=pky-p0y, dz=pkz-p0z;
  float c1x=n0y*dz-n0z*dy, c1y=n0z*dx-n0x*dz, c1z=n0x*dy-n0y*dx;
  float a1 = atan2f(sqrtf(c1x*c1x+c1y*c1y+c1z*c1z+1e-12f), n0x*dx+n0y*dy+n0z*dz);
  float c2x=nky*dz-nkz*dy, c2y=nkz*dx-nkx*dz, c2z=nkx*dy-nky*dx;
  float a2 = atan2f(sqrtf(c2x*c2x+c2y*c2y+c2z*c2z+1e-12f), nkx*dx+nky*dy+nkz*dz);
  float c3x=n0y*nkz-n0z*nky, c3y=n0z*nkx-n0x*nkz, c3z=n0x*nky-n0y*nkx;
  float a3 = atan2f(sqrtf(c3x*c3x+c3y*c3y+c3z*c3z+1e-12f), n0x*nkx+n0y*nky+n0z*nkz);
  float dist = sqrtf(dx*dx+dy*dy+dz*dz+1e-12f);
  x0[0]=a1; x0[1]=a2; x0[2]=a3; x0[3]=dist; x0[4]=dist;
}

// stats: per-channel sum & sumsq across block -> atomicAdd to global acc
template<int C>
__device__ __forceinline__ void stats_reduce(const float* y, float* __restrict__ accG, int tid, float* lst){
  const int w = tid>>6, lane = tid&63;
  #pragma unroll
  for (int j=0;j<C;++j){
    float sv=y[j], sq=y[j]*y[j];
    #pragma unroll
    for (int off=1;off<64;off<<=1){ sv+=__shfl_xor(sv,off); sq+=__shfl_xor(sq,off); }
    if (lane==0){ lst[w*2*C+j]=sv; lst[w*2*C+C+j]=sq; }
  }
  __syncthreads();
  if (tid<C){
    float a=lst[tid]+lst[2*C+tid]+lst[4*C+tid]+lst[6*C+tid];
    float q=lst[C+tid]+lst[3*C+tid]+lst[5*C+tid]+lst[7*C+tid];
    atomicAdd(&accG[tid], a);
    atomicAdd(&accG[128+tid], q);
  }
}

__device__ __forceinline__ void load_feat_row(const float* __restrict__ feat, size_t s,
    const int* __restrict__ knn, float* f){
  int bm=(int)(s>>5), k=(int)(s&31), b=bm>>11;
  int ik = knn[(size_t)bm*K_ + k] & (N_-1);
  const float4* fp = (const float4*)(feat + ((size_t)b*N_ + ik)*64);
  #pragma unroll
  for (int q=0;q<16;++q){
    float4 v = fp[q]; int c=q*4;
    f[c]=v.x; f[c+1]=v.y; f[c+2]=v.z; f[c+3]=v.w;
  }
}

// ---------------- stats passes (recompute chain in registers) ----------------
__global__ __launch_bounds__(256) void pass1(const float* __restrict__ pose, const float* __restrict__ normal,
    const int* __restrict__ knn, const float* __restrict__ W1, const float* __restrict__ b1, float* __restrict__ acc){
  __shared__ float lst[1024];
  int tid=threadIdx.x; size_t s=(size_t)blockIdx.x*256+tid;
  float x0[5]; ppf_feats(pose,normal,knn,s,x0);
  float y1[64]; dense<5,64>(W1,b1,x0,y1);
  stats_reduce<64>(y1, acc, tid, lst);
}

__global__ __launch_bounds__(256) void pass2(const float* __restrict__ pose, const float* __restrict__ normal,
    const int* __restrict__ knn, const float* __restrict__ W1, const float* __restrict__ b1,
    const float* __restrict__ W2, const float* __restrict__ b2, const float* __restrict__ scsh, float* __restrict__ acc){
  __shared__ float lst[1024];
  int tid=threadIdx.x; size_t s=(size_t)blockIdx.x*256+tid;
  float x0[5]; ppf_feats(pose,normal,knn,s,x0);
  float y1[64]; dense<5,64>(W1,b1,x0,y1);  bnrelu<64>(scsh+0, y1);
  float y2[64]; dense<64,64>(W2,b2,y1,y2);
  stats_reduce<64>(y2, acc, tid, lst);
}

__global__ __launch_bounds__(256) void pass3(const float* __restrict__ pose, const float* __restrict__ normal,
    const float* __restrict__ feat, const int* __restrict__ knn,
    const float* __restrict__ W1, const float* __restrict__ b1,
    const float* __restrict__ W2, const float* __restrict__ b2,
    const float* __restrict__ W3, const float* __restrict__ b3,
    const float* __restrict__ scsh, float* __restrict__ acc){
  __shared__ float lst[1024];
  int tid=threadIdx.x; size_t s=(size_t)blockIdx.x*256+tid;
  float x0[5]; ppf_feats(pose,normal,knn,s,x0);
  float y1[64]; dense<5,64>(W1,b1,x0,y1);  bnrelu<64>(scsh+0, y1);
  float y2[64]; dense<64,64>(W2,b2,y1,y2); bnrelu<64>(scsh+256, y2);
  float f[64]; load_feat_row(feat, s, knn, f);
  float y3[64]; dense2<64,64,64>(W3,b3,f,y2,y3);
  stats_reduce<64>(y3, acc, tid, lst);
}

__global__ __launch_bounds__(256) void pass4(const float* __restrict__ pose, const float* __restrict__ normal,
    const float* __restrict__ feat, const int* __restrict__ knn,
    const float* __restrict__ W1, const float* __restrict__ b1,
    const float* __restrict__ W2, const float* __restrict__ b2,
    const float* __restrict__ W3, const float* __restrict__ b3,
    const float* __restrict__ W4, const float* __restrict__ b4,
    const float* __restrict__ scsh, float* __restrict__ acc){
  __shared__ float lst[1024];
  int tid=threadIdx.x; size_t s=(size_t)blockIdx.x*256+tid;
  float x0[5]; ppf_feats(pose,normal,knn,s,x0);
  float y1[64]; dense<5,64>(W1,b1,x0,y1);  bnrelu<64>(scsh+0, y1);
  float y2[64]; dense<64,64>(W2,b2,y1,y2); bnrelu<64>(scsh+256, y2);
  float f[64]; load_feat_row(feat, s, knn, f);
  float y3[64]; dense2<64,64,64>(W3,b3,f,y2,y3); bnrelu<64>(scsh+512, y3);
  float y4[64]; dense<64,64>(W4,b4,y3,y4);
  stats_reduce<64>(y4, acc, tid, lst);
}

__global__ __launch_bounds__(256) void pass5(const float* __restrict__ pose, const float* __restrict__ normal,
    const float* __restrict__ feat, const int* __restrict__ knn,
    const float* __restrict__ W1, const float* __restrict__ b1,
    const float* __restrict__ W2, const float* __restrict__ b2,
    const float* __restrict__ W3, const float* __restrict__ b3,
    const float* __restrict__ W4, const float* __restrict__ b4,
    const float* __restrict__ W5, const float* __restrict__ b5,
    const float* __restrict__ scsh, float* __restrict__ acc){
  __shared__ float lst[1024];
  int tid=threadIdx.x; size_t s=(size_t)blockIdx.x*256+tid;
  float x0[5]; ppf_feats(pose,normal,knn,s,x0);
  float y1[64]; dense<5,64>(W1,b1,x0,y1);  bnrelu<64>(scsh+0, y1);
  float y2[64]; dense<64,64>(W2,b2,y1,y2); bnrelu<64>(scsh+256, y2);
  float f[64]; load_feat_row(feat, s, knn, f);
  float y3[64]; dense2<64,64,64>(W3,b3,f,y2,y3); bnrelu<64>(scsh+512, y3);
  float y4[64]; dense<64,64>(W4,b4,y3,y4);       bnrelu<64>(scsh+768, y4);
  float y5[128]; dense<64,128>(W5,b5,y4,y5);
  stats_reduce<128>(y5, acc, tid, lst);
}

// ---------------- final pass: chain + bn5 + relu + max over k -> new_feat (f32) ----------------
__global__ __launch_bounds__(256) void pass6(const float* __restrict__ pose, const float* __restrict__ normal,
    const float* __restrict__ feat, const int* __restrict__ knn,
    const float* __restrict__ W1, const float* __restrict__ b1,
    const float* __restrict__ W2, const float* __restrict__ b2,
    const float* __restrict__ W3, const float* __restrict__ b3,
    const float* __restrict__ W4, const float* __restrict__ b4,
    const float* __restrict__ W5, const float* __restrict__ b5,
    const float* __restrict__ scsh, float* __restrict__ out1){
  int tid=threadIdx.x; size_t s=(size_t)blockIdx.x*256+tid;
  float x0[5]; ppf_feats(pose,normal,knn,s,x0);
  float y1[64]; dense<5,64>(W1,b1,x0,y1);  bnrelu<64>(scsh+0, y1);
  float y2[64]; dense<64,64>(W2,b2,y1,y2); bnrelu<64>(scsh+256, y2);
  float f[64]; load_feat_row(feat, s, knn, f);
  float y3[64]; dense2<64,64,64>(W3,b3,f,y2,y3); bnrelu<64>(scsh+512, y3);
  float y4[64]; dense<64,64>(W4,b4,y3,y4);       bnrelu<64>(scsh+768, y4);
  int bm=(int)(s>>5), k=(int)(s&31);
  const float* sc5 = scsh + 1024;
  #pragma unroll
  for (int j4=0;j4<32;++j4){
    float4 a = *(const float4*)(b5 + j4*4);
    #pragma unroll
    for (int c=0;c<64;++c){
      float4 w = *(const float4*)(W5 + c*128 + j4*4);
      a.x = fmaf(y4[c], w.x, a.x); a.y = fmaf(y4[c], w.y, a.y);
      a.z = fmaf(y4[c], w.z, a.z); a.w = fmaf(y4[c], w.w, a.w);
    }
    float r0 = fmaxf(fmaf(sc5[j4*4+0], a.x, sc5[128+j4*4+0]), 0.f);
    float r1 = fmaxf(fmaf(sc5[j4*4+1], a.y, sc5[128+j4*4+1]), 0.f);
    float r2 = fmaxf(fmaf(sc5[j4*4+2], a.z, sc5[128+j4*4+2]), 0.f);
    float r3 = fmaxf(fmaf(sc5[j4*4+3], a.w, sc5[128+j4*4+3]), 0.f);
    #pragma unroll
    for (int off=1;off<32;off<<=1){
      r0 = fmaxf(r0, __shfl_xor(r0, off));
      r1 = fmaxf(r1, __shfl_xor(r1, off));
      r2 = fmaxf(r2, __shfl_xor(r2, off));
      r3 = fmaxf(r3, __shfl_xor(r3, off));
    }
    if (k==0){
      size_t o = (size_t)bm*128 + j4*4;
      out1[o+0]=r0; out1[o+1]=r1; out1[o+2]=r2; out1[o+3]=r3;
    }
  }
}

// ---------------- finalize BN stats for one layer: acc -> scale/shift ----------------
__global__ __launch_bounds__(128) void fin_kernel(const float* __restrict__ accL, const float* __restrict__ g,
    const float* __restrict__ be, float* __restrict__ scshL, int C){
  int j = threadIdx.x;
  if (j >= C) return;
  double S = (double)S_TOT;
  double mu = (double)accL[j]/S;
  double var = (double)accL[128+j]/S - mu*mu;
  double sc = (double)g[j] / sqrt(var + 1e-5);
  scshL[j] = (float)sc;
  scshL[128+j] = (float)((double)be[j] - mu*sc);
}

extern "C" void kernel_launch(void* const* d_in, const int* in_sizes, int n_in,
                              void* d_out, int out_size, void* d_ws, size_t ws_size,
                              hipStream_t stream) {
  (void)in_sizes; (void)n_in; (void)out_size; (void)ws_size;
  const float* pose   = (const float*)d_in[0];
  const float* feat   = (const float*)d_in[1];
  const float* normal = (const float*)d_in[2];
  const float* sh     = (const float*)d_in[3];
  const float* rw1=(const float*)d_in[4];  const float* rb1=(const float*)d_in[5];
  const float* rg1=(const float*)d_in[6];  const float* rbe1=(const float*)d_in[7];
  const float* rw2=(const float*)d_in[8];  const float* rb2=(const float*)d_in[9];
  const float* rg2=(const float*)d_in[10]; const float* rbe2=(const float*)d_in[11];
  const float* pw1=(const float*)d_in[12]; const float* pb1=(const float*)d_in[13];
  const float* pg1=(const float*)d_in[14]; const float* pbe1=(const float*)d_in[15];
  const float* pw2=(const float*)d_in[16]; const float* pb2=(const float*)d_in[17];
  const float* pg2=(const float*)d_in[18]; const float* pbe2=(const float*)d_in[19];
  const float* pw3=(const float*)d_in[20]; const float* pb3=(const float*)d_in[21];
  const float* pg3=(const float*)d_in[22]; const float* pbe3=(const float*)d_in[23];

  char* W = (char*)d_ws;
  int*   fps   = (int*)(W + OFF_FPS);
  float* npf   = (float*)(W + OFF_NP);
  int*   knn   = (int*)(W + OFF_KNN);
  float* acc   = (float*)(W + OFF_ACC);
  float* scsh  = (float*)(W + OFF_SCSH);
  float* out   = (float*)d_out;

  init_kernel<<<dim3(5), dim3(256), 0, stream>>>(acc);
  fps_kernel<<<dim3(B_), dim3(512), 0, stream>>>(pose, fps);
  gather_kernel<<<dim3(BM_/256), dim3(256), 0, stream>>>(pose, normal, sh, fps, out, npf);
  knn_kernel<<<dim3(BM_), dim3(256), 0, stream>>>(pose, npf, knn);

  const int G = S_TOT/256;
  pass1<<<dim3(G), dim3(256), 0, stream>>>(pose, normal, knn, rw1, rb1, acc+0);
  fin_kernel<<<dim3(1), dim3(128), 0, stream>>>(acc+0, rg1, rbe1, scsh+0, 64);
  pass2<<<dim3(G), dim3(256), 0, stream>>>(pose, normal, knn, rw1, rb1, rw2, rb2, scsh, acc+256);
  fin_kernel<<<dim3(1), dim3(128), 0, stream>>>(acc+256, rg2, rbe2, scsh+256, 64);
  pass3<<<dim3(G), dim3(256), 0, stream>>>(pose, normal, feat, knn, rw1, rb1, rw2, rb2, pw1, pb1, scsh, acc+512);
  fin_kernel<<<dim3(1), dim3(128), 0, stream>>>(acc+512, pg1, pbe1, scsh+512, 64);
  pass4<<<dim3(G), dim3(256), 0, stream>>>(pose, normal, feat, knn, rw1, rb1, rw2, rb2, pw1, pb1, pw2, pb2, scsh, acc+768);
  fin_kernel<<<dim3(1), dim3(128), 0, stream>>>(acc+768, pg2, pbe2, scsh+768, 64);
  pass5<<<dim3(G), dim3(256), 0, stream>>>(pose, normal, feat, knn, rw1, rb1, rw2, rb2, pw1, pb1, pw2, pb2, pw3, pb3, scsh, acc+1024);
  fin_kernel<<<dim3(1), dim3(128), 0, stream>>>(acc+1024, pg3, pbe3, scsh+1024, 128);
  pass6<<<dim3(G), dim3(256), 0, stream>>>(pose, normal, feat, knn, rw1, rb1, rw2, rb2, pw1, pb1, pw2, pb2, pw3, pb3, scsh, out + OUT1_OFF);
}